// Round 14
// baseline (111.499 us; speedup 1.0000x reference)
//
#include <hip/hip_runtime.h>
#include <hip/hip_bf16.h>

// MultiHeadCausalSelfAttention: B=2, N=4096, C=512, H=8, D=64, causal, fp32 in/out.
// Pipeline: cvt(fused) -> QKV GEMM (scatter Q, frag-layout K/V) -> attn(+merge) -> proj.
// R14: split-KV x{1,2,3,4} (all blocks <=17 iters, 5120 blocks) when ws_size allows
//      (po at ws tail); else exact R13 fallback. Attn body math unchanged (proven).

typedef __attribute__((ext_vector_type(8))) short s16x8;   // 8 bf16 = one MFMA A/B frag
typedef __attribute__((ext_vector_type(4))) float f32x4;   // one MFMA C/D frag

#define QSCALE 0.18033688011112042f  // D^-0.5 * log2(e), folded into Q

__device__ __forceinline__ ushort f2bf(float f) {
  unsigned u = __float_as_uint(f);
  u = (u + 0x7FFFu + ((u >> 16) & 1u)) >> 16;  // RNE
  return (ushort)u;
}

__device__ __forceinline__ unsigned cvt_pk_bf16(float a, float b) {
  unsigned r;
  asm("v_cvt_pk_bf16_f32 %0, %1, %2" : "=v"(r) : "v"(a), "v"(b));
  return r;  // low16 = bf16(a), high16 = bf16(b)
}

__device__ __forceinline__ float bflo(unsigned u) { return __uint_as_float(u << 16); }
__device__ __forceinline__ float bfhi(unsigned u) { return __uint_as_float(u & 0xffff0000u); }

// One fused cvt for x (1048576 float4), w_qkv (196608), w_proj (65536).
__global__ __launch_bounds__(256) void cvt_all(const float* __restrict__ x,
                                               const float* __restrict__ wq,
                                               const float* __restrict__ wp,
                                               ushort* __restrict__ xb,
                                               ushort* __restrict__ wqb,
                                               ushort* __restrict__ wpb) {
  int i = blockIdx.x * 256 + threadIdx.x;
  const float* src;
  ushort* dst;
  int off;
  if (i < 1048576) {
    src = x; dst = xb; off = i;
  } else if (i < 1245184) {
    src = wq; dst = wqb; off = i - 1048576;
  } else {
    src = wp; dst = wpb; off = i - 1245184;
  }
  float4 v = reinterpret_cast<const float4*>(src)[off];
  ushort4 o;
  o.x = f2bf(v.x); o.y = f2bf(v.y); o.z = f2bf(v.z); o.w = f2bf(v.w);
  reinterpret_cast<ushort4*>(dst)[off] = o;
}

// C = A[M,512] @ W[Nout,512]^T, bf16 MFMA, 128x128 tile, 4 waves (2x2), BK=32.
// 2-phase double-buffer: STAGE(t+1) issued before compute(t), one barrier/iter.
// EPI 0: Q/K/V scatter. EPI 1: fp32 out + bias.
template <int EPI>
__global__ __launch_bounds__(256) void gemm_bt(const ushort* __restrict__ A,
                                               const ushort* __restrict__ W,
                                               ushort* __restrict__ q_ws,
                                               ushort* __restrict__ k_ws,
                                               ushort* __restrict__ vt_ws,
                                               float* __restrict__ outf,
                                               const float* __restrict__ bias) {
  __shared__ ushort As[2][128 * 32];
  __shared__ ushort Bs[2][128 * 32];
  const int tid = threadIdx.x;
  const int lane = tid & 63, wv = tid >> 6;
  const int wm = wv >> 1, wn = wv & 1;
  const int l15 = lane & 15, g = lane >> 4;
  const int tm = blockIdx.y * 128, tn = blockIdx.x * 128;

  f32x4 acc[4][4] = {};

#define GSTAGE(BUF, K0)                                                                    \
  do {                                                                                     \
    _Pragma("unroll") for (int it = 0; it < 2; ++it) {                                     \
      int slot = it * 256 + tid;                                                           \
      int row = slot >> 2;                                                                 \
      int ch = (slot & 3) ^ ((row >> 1) & 3);                                              \
      const int sb = (it * 256 + wv * 64) * 8; /* wave-uniform LDS base (ushorts) */       \
      __builtin_amdgcn_global_load_lds(                                                    \
          (const __attribute__((address_space(1))) void*)(A + (size_t)(tm + row) * 512 +   \
                                                          (K0) + ch * 8),                  \
          (__attribute__((address_space(3))) void*)(&As[BUF][0] + sb), 16, 0, 0);          \
      __builtin_amdgcn_global_load_lds(                                                    \
          (const __attribute__((address_space(1))) void*)(W + (size_t)(tn + row) * 512 +   \
                                                          (K0) + ch * 8),                  \
          (__attribute__((address_space(3))) void*)(&Bs[BUF][0] + sb), 16, 0, 0);          \
    }                                                                                      \
  } while (0)

  GSTAGE(0, 0);
  __syncthreads();
  int cur = 0;
  for (int t = 0; t < 16; ++t) {
    if (t < 15) GSTAGE(cur ^ 1, (t + 1) * 32);  // next tile in flight during compute
    s16x8 af[4], bfr[4];
#pragma unroll
    for (int i = 0; i < 4; ++i) {
      int Ra = wm * 64 + i * 16 + l15;
      af[i] = reinterpret_cast<const s16x8*>(&As[cur][0])[Ra * 4 + (g ^ ((Ra >> 1) & 3))];
      int Rb = wn * 64 + i * 16 + l15;
      bfr[i] = reinterpret_cast<const s16x8*>(&Bs[cur][0])[Rb * 4 + (g ^ ((Rb >> 1) & 3))];
    }
#pragma unroll
    for (int mi = 0; mi < 4; ++mi)
#pragma unroll
      for (int ni = 0; ni < 4; ++ni)
        acc[mi][ni] =
            __builtin_amdgcn_mfma_f32_16x16x32_bf16(af[mi], bfr[ni], acc[mi][ni], 0, 0, 0);
    __syncthreads();  // drains vmcnt (staged loads) + lgkm; both buffers safe
    cur ^= 1;
  }
#undef GSTAGE

  // C/D layout: col = lane&15, row = (lane>>4)*4 + reg   [measured m89/m91]
  const int rowb = tm + wm * 64 + g * 4;
  const int colb = tn + wn * 64 + l15;
#pragma unroll
  for (int mi = 0; mi < 4; ++mi) {
#pragma unroll
    for (int ni = 0; ni < 4; ++ni) {
      int r0 = rowb + mi * 16;
      int col = colb + ni * 16;
      if (EPI == 0) {
        int i3 = col >> 9, h = (col >> 6) & 7, d = col & 63;
        int b = r0 >> 12;
        int bh = b * 8 + h;
        if (i3 == 2) {
          int n0 = r0 & 4095;
          int kt = n0 >> 6, ce = (n0 >> 5) & 1, ge = (n0 >> 3) & 3, je = n0 & 7;
          int nbe = d >> 4, le = d & 15;
          ushort4 pk;
          pk.x = f2bf(acc[mi][ni][0]);
          pk.y = f2bf(acc[mi][ni][1]);
          pk.z = f2bf(acc[mi][ni][2]);
          pk.w = f2bf(acc[mi][ni][3]);
          *reinterpret_cast<ushort4*>(
              vt_ws + (((size_t)bh * 64 + kt) * 8 + nbe * 2 + ce) * 512 + (ge * 16 + le) * 8 +
              je) = pk;
        } else if (i3 == 1) {
          int ce = d >> 5, ge = (d >> 3) & 3, je = d & 7;
#pragma unroll
          for (int r = 0; r < 4; ++r) {
            int n = (r0 + r) & 4095;
            int kt = n >> 6, le = n & 15, nbe = (n >> 4) & 3;
            k_ws[(((size_t)bh * 64 + kt) * 8 + nbe * 2 + ce) * 512 + (ge * 16 + le) * 8 + je] =
                f2bf(acc[mi][ni][r]);
          }
        } else {
          int n0 = r0 & 4095;
#pragma unroll
          for (int r = 0; r < 4; ++r)
            q_ws[((size_t)bh * 4096 + (n0 + r)) * 64 + d] = f2bf(acc[mi][ni][r] * QSCALE);
        }
      } else {
#pragma unroll
        for (int r = 0; r < 4; ++r)
          outf[(size_t)(r0 + r) * 512 + col] = acc[mi][ni][r] + bias[col];
      }
    }
  }
}

// Flash attention, causal. 64-thread (1-wave) blocks, QBLK=32, proven body.
// MODE 0 (R13): 3072 blocks, heavy(qt>=64) split x2. MODE 1: 5120 blocks,
// split x{1,2,3,4} so every block is <=17 iters (better drain/overlap).
// XCD-chunked: p = L&7 owns bh {2p, 2p+1}; items descending-duration (LPT).
template <int MODE>
__global__ __launch_bounds__(64, 2) void attn_kernel(const ushort* __restrict__ Q,
                                                     const ushort* __restrict__ Kk,
                                                     const ushort* __restrict__ Vt,
                                                     ushort* __restrict__ O,
                                                     ushort* __restrict__ po,
                                                     float* __restrict__ ml) {
  __shared__ ushort P_lds[32 * 64];  // rows = 32 queries, cols = 64 keys (swizzled)
  const int lane = threadIdx.x & 63;
  const int l15 = lane & 15, g = lane >> 4;
  const int L = blockIdx.x;
  const int p = L & 7, j2 = L >> 3;      // consecutive L round-robin XCDs -> p = XCD
  const int bh = p * 2 + (j2 & 1);       // each XCD: 2 bh only (K/V in its L2)
  int qt, klo, khi, slot = 0;
  bool partial;
  if (MODE == 0) {
    const int i = j2 >> 1;               // 0..191
    const int r = i / 3;
    const int kind = i - r * 3;          // 0:heavy-lo 1:heavy-hi 2:light
    if (kind == 2) {
      qt = 63 - r;
      partial = false;
      klo = 0;
      khi = qt >> 1;
    } else {
      qt = 127 - r;
      partial = true;
      const int ktm = qt >> 1;
      const int mid = (ktm + 2) >> 1;
      klo = kind ? mid : 0;
      khi = kind ? ktm : (mid - 1);
      slot = (bh * 64 + (qt - 64)) * 2 + kind;
    }
  } else {
    const int i = j2 >> 1;               // 0..319, descending duration
    int part, S;
    if (i < 128) {
      qt = 127 - (i >> 2); part = i & 3; S = 4;          // qt in [96,128)
    } else if (i < 224) {
      int j = i - 128; int q3 = j / 3;
      qt = 95 - q3; part = j - q3 * 3; S = 3;            // qt in [64,96)
    } else if (i < 288) {
      int j = i - 224;
      qt = 63 - (j >> 1); part = j & 1; S = 2;           // qt in [32,64)
    } else {
      qt = 31 - (i - 288); part = 0; S = 1;              // qt in [0,32)
    }
    const int T = (qt >> 1) + 1;
    klo = part * T / S;
    khi = (part + 1) * T / S - 1;
    partial = (S > 1);
    if (partial) slot = (bh * 96 + (qt - 32)) * 4 + part;
  }
  const int ktmax = qt >> 1;  // diagonal tile index (mask condition)
  const int qw = qt * 32;
  const size_t baseQ = (size_t)bh * 4096 * 64;

  // Q B-frags: sub s -> query qw + s*16 + l15, k-elems c*32 + g*8 + j
  s16x8 aq[2][2];
#pragma unroll
  for (int s = 0; s < 2; ++s) {
    const ushort* qp = Q + baseQ + (size_t)(qw + s * 16 + l15) * 64 + g * 8;
    aq[s][0] = *reinterpret_cast<const s16x8*>(qp);
    aq[s][1] = *reinterpret_cast<const s16x8*>(qp + 32);
  }

  f32x4 o[2][4] = {};
  float m[2] = {-1e30f, -1e30f};
  float l[2] = {0.f, 0.f};  // per-lane PARTIAL sums (reduced in epilogue)
  const int swz = (l15 & 7) << 3;  // XOR swizzle in ushort units (16B granule)
  const ushort* kb = Kk + ((size_t)bh * 64) * 4096 + lane * 8;
  const ushort* vb = Vt + ((size_t)bh * 64) * 4096 + lane * 8;

  s16x8 kfA[8], kfB[8];
#pragma unroll
  for (int t = 0; t < 8; ++t)
    kfA[t] = *reinterpret_cast<const s16x8*>(kb + (size_t)klo * 4096 + t * 512);

#define ATTN_STEP(KC, KN, KT)                                                             \
  do {                                                                                    \
    const ushort* vp = vb + (size_t)(KT) * 4096;                                          \
    s16x8 vf[8];                                                                          \
    _Pragma("unroll") for (int t = 0; t < 8; ++t)                                         \
        vf[t] = *reinterpret_cast<const s16x8*>(vp + t * 512);                            \
    const int knx = ((KT) >= khi) ? khi : ((KT) + 1);                                     \
    const ushort* kpn = kb + (size_t)knx * 4096;                                          \
    _Pragma("unroll") for (int t = 0; t < 8; ++t)                                         \
        KN[t] = *reinterpret_cast<const s16x8*>(kpn + t * 512);                           \
    f32x4 st[2][4] = {};                                                                  \
    __builtin_amdgcn_s_setprio(1);                                                        \
    _Pragma("unroll") for (int nb = 0; nb < 4; ++nb) {                                    \
      _Pragma("unroll") for (int s = 0; s < 2; ++s) {                                     \
        st[s][nb] = __builtin_amdgcn_mfma_f32_16x16x32_bf16(KC[nb * 2 + 0], aq[s][0],     \
                                                            st[s][nb], 0, 0, 0);         \
        st[s][nb] = __builtin_amdgcn_mfma_f32_16x16x32_bf16(KC[nb * 2 + 1], aq[s][1],     \
                                                            st[s][nb], 0, 0, 0);         \
      }                                                                                   \
    }                                                                                     \
    __builtin_amdgcn_s_setprio(0);                                                        \
    if ((KT) == ktmax) { /* diagonal: mask key > query */                                 \
      const int k0d = (KT) * 64;                                                          \
      _Pragma("unroll") for (int s = 0; s < 2; ++s)                                       \
          _Pragma("unroll") for (int nb = 0; nb < 4; ++nb)                                \
              _Pragma("unroll") for (int r2 = 0; r2 < 4; ++r2)                            \
                  if (k0d + nb * 16 + g * 4 + r2 > qw + s * 16 + l15)                     \
                    st[s][nb][r2] = -1e30f;                                               \
    }                                                                                     \
    _Pragma("unroll") for (int s = 0; s < 2; ++s) {                                       \
      float a0 = fmaxf(fmaxf(st[s][0][0], st[s][0][1]), fmaxf(st[s][0][2], st[s][0][3])); \
      float a1 = fmaxf(fmaxf(st[s][1][0], st[s][1][1]), fmaxf(st[s][1][2], st[s][1][3])); \
      float a2 = fmaxf(fmaxf(st[s][2][0], st[s][2][1]), fmaxf(st[s][2][2], st[s][2][3])); \
      float a3 = fmaxf(fmaxf(st[s][3][0], st[s][3][1]), fmaxf(st[s][3][2], st[s][3][3])); \
      float pm = fmaxf(fmaxf(a0, a1), fmaxf(a2, a3)); /* lane-local max */                \
      if (!__all(pm - m[s] <= 8.0f)) { /* rare: full reduce + rescale */                  \
        float pmf = fmaxf(pm, __shfl_xor(pm, 16));                                        \
        pmf = fmaxf(pmf, __shfl_xor(pmf, 32));                                            \
        const float mn = fmaxf(m[s], pmf);                                                \
        const float al = __builtin_amdgcn_exp2f(m[s] - mn);                               \
        l[s] *= al;                                                                       \
        m[s] = mn;                                                                        \
        _Pragma("unroll") for (int nb = 0; nb < 4; ++nb)                                  \
            _Pragma("unroll") for (int r2 = 0; r2 < 4; ++r2) o[s][nb][r2] *= al;          \
      }                                                                                   \
      float rs = 0.f;                                                                     \
      _Pragma("unroll") for (int nb = 0; nb < 4; ++nb) {                                  \
        float p0 = __builtin_amdgcn_exp2f(st[s][nb][0] - m[s]);                           \
        float p1 = __builtin_amdgcn_exp2f(st[s][nb][1] - m[s]);                           \
        float p2 = __builtin_amdgcn_exp2f(st[s][nb][2] - m[s]);                           \
        float p3 = __builtin_amdgcn_exp2f(st[s][nb][3] - m[s]);                           \
        rs += (p0 + p1) + (p2 + p3);                                                      \
        uint2 w;                                                                          \
        w.x = cvt_pk_bf16(p0, p1);                                                        \
        w.y = cvt_pk_bf16(p2, p3);                                                        \
        *reinterpret_cast<uint2*>(P_lds + (s * 16 + l15) * 64 +                           \
                                  ((nb * 16 + g * 4) ^ swz)) = w;                         \
      }                                                                                   \
      l[s] += rs;                                                                         \
    }                                                                                     \
    s16x8 pa[2][2];                                                                       \
    _Pragma("unroll") for (int s = 0; s < 2; ++s)                                         \
        _Pragma("unroll") for (int c = 0; c < 2; ++c)                                     \
            pa[s][c] = *reinterpret_cast<const s16x8*>(P_lds + (s * 16 + l15) * 64 +      \
                                                       ((c * 32 + g * 8) ^ swz));         \
    __builtin_amdgcn_s_setprio(1);                                                        \
    _Pragma("unroll") for (int nb = 0; nb < 4; ++nb) {                                    \
      _Pragma("unroll") for (int s = 0; s < 2; ++s) {                                     \
        o[s][nb] = __builtin_amdgcn_mfma_f32_16x16x32_bf16(vf[nb * 2 + 0], pa[s][0],      \
                                                           o[s][nb], 0, 0, 0);            \
        o[s][nb] = __builtin_amdgcn_mfma_f32_16x16x32_bf16(vf[nb * 2 + 1], pa[s][1],      \
                                                           o[s][nb], 0, 0, 0);            \
      }                                                                                   \
    }                                                                                     \
    __builtin_amdgcn_s_setprio(0);                                                        \
  } while (0)

  int kt = klo;
  for (;;) {
    ATTN_STEP(kfA, kfB, kt);
    if (++kt > khi) break;
    ATTN_STEP(kfB, kfA, kt);
    if (++kt > khi) break;
  }
#undef ATTN_STEP

  // Reduce partial l across the 4 lane-groups (row sum per query l15).
  float lr[2];
#pragma unroll
  for (int s = 0; s < 2; ++s) {
    float ls = l[s];
    ls += __shfl_xor(ls, 16);
    ls += __shfl_xor(ls, 32);
    lr[s] = ls;
  }

  if (!partial) {
    // O^T: lane owns query qw + s*16 + l15; d = nb*16 + g*4 + r2
    const int b = bh >> 3, h = bh & 7;
#pragma unroll
    for (int s = 0; s < 2; ++s) {
      const float linv = 1.0f / lr[s];
      const size_t rowo = (size_t)(b * 4096 + qw + s * 16 + l15) * 512 + h * 64;
#pragma unroll
      for (int nb = 0; nb < 4; ++nb) {
        uint2 pk;
        pk.x = cvt_pk_bf16(o[s][nb][0] * linv, o[s][nb][1] * linv);
        pk.y = cvt_pk_bf16(o[s][nb][2] * linv, o[s][nb][3] * linv);
        *reinterpret_cast<uint2*>(&O[rowo + nb * 16 + g * 4]) = pk;
      }
    }
  } else {
    // Normalized bf16 partial O + (m, l) per row.
#pragma unroll
    for (int s = 0; s < 2; ++s) {
      const float linv = 1.0f / lr[s];
      const int row = s * 16 + l15;
      const size_t pbase = ((size_t)slot * 32 + row) * 64;
#pragma unroll
      for (int nb = 0; nb < 4; ++nb) {
        uint2 pk;
        pk.x = cvt_pk_bf16(o[s][nb][0] * linv, o[s][nb][1] * linv);
        pk.y = cvt_pk_bf16(o[s][nb][2] * linv, o[s][nb][3] * linv);
        *reinterpret_cast<uint2*>(po + pbase + nb * 16 + g * 4) = pk;
      }
      if (g == 0) {
        float2 v;
        v.x = m[s];
        v.y = lr[s];
        *reinterpret_cast<float2*>(ml + ((size_t)slot * 32 + row) * 2) = v;
      }
    }
  }
}

// MODE-0 merge (two halves). 1024 blocks x 64 threads.
__global__ __launch_bounds__(64) void attn_merge(const ushort* __restrict__ po,
                                                 const float* __restrict__ ml,
                                                 ushort* __restrict__ O) {
  const int L = blockIdx.x, tid = threadIdx.x;
  const int p = L & 7, q2 = L >> 3;
  const int bh = p * 2 + (q2 & 1);
  const int qt = 64 + (q2 >> 1);
  const int t = bh * 64 + (qt - 64);
  const int row = tid >> 1, dh = (tid & 1) * 32;
  const float2 ml0 = *reinterpret_cast<const float2*>(ml + ((size_t)(t * 2 + 0) * 32 + row) * 2);
  const float2 ml1 = *reinterpret_cast<const float2*>(ml + ((size_t)(t * 2 + 1) * 32 + row) * 2);
  const float ms = fmaxf(ml0.x, ml1.x);
  const float w0 = __builtin_amdgcn_exp2f(ml0.x - ms) * ml0.y;
  const float w1 = __builtin_amdgcn_exp2f(ml1.x - ms) * ml1.y;
  const float inv = 1.0f / (w0 + w1);
  const float c0 = w0 * inv, c1 = w1 * inv;
  const int b = bh >> 3, h = bh & 7;
  const size_t rowo = (size_t)(b * 4096 + qt * 32 + row) * 512 + h * 64 + dh;
  const ushort* p0 = po + ((size_t)(t * 2 + 0) * 32 + row) * 64 + dh;
  const ushort* p1 = po + ((size_t)(t * 2 + 1) * 32 + row) * 64 + dh;
#pragma unroll
  for (int j = 0; j < 4; ++j) {
    uint4 a = reinterpret_cast<const uint4*>(p0)[j];
    uint4 bb = reinterpret_cast<const uint4*>(p1)[j];
    uint4 out;
    out.x = cvt_pk_bf16(c0 * bflo(a.x) + c1 * bflo(bb.x), c0 * bfhi(a.x) + c1 * bfhi(bb.x));
    out.y = cvt_pk_bf16(c0 * bflo(a.y) + c1 * bflo(bb.y), c0 * bfhi(a.y) + c1 * bfhi(bb.y));
    out.z = cvt_pk_bf16(c0 * bflo(a.z) + c1 * bflo(bb.z), c0 * bfhi(a.z) + c1 * bfhi(bb.z));
    out.w = cvt_pk_bf16(c0 * bflo(a.w) + c1 * bflo(bb.w), c0 * bfhi(a.w) + c1 * bfhi(bb.w));
    reinterpret_cast<uint4*>(&O[rowo])[j] = out;
  }
}

// MODE-1 merge (up to 4 parts, guarded). 1536 blocks x 64 threads.
__global__ __launch_bounds__(64) void attn_merge4(const ushort* __restrict__ po,
                                                  const float* __restrict__ ml,
                                                  ushort* __restrict__ O) {
  const int M = blockIdx.x, tid = threadIdx.x;
  const int p = M & 7, q2 = M >> 3;
  const int bh = p * 2 + (q2 & 1);
  const int ti = q2 >> 1;            // 0..95
  const int qt = 32 + ti;
  const int S = (qt >= 96) ? 4 : (qt >= 64) ? 3 : 2;
  const int base = (bh * 96 + ti) * 4;
  const int row = tid >> 1, dh = (tid & 1) * 32;
  const float2 v0 = *reinterpret_cast<const float2*>(ml + ((size_t)(base + 0) * 32 + row) * 2);
  const float2 v1 = *reinterpret_cast<const float2*>(ml + ((size_t)(base + 1) * 32 + row) * 2);
  float2 v2 = {-1e30f, 0.f}, v3 = {-1e30f, 0.f};
  if (S > 2) v2 = *reinterpret_cast<const float2*>(ml + ((size_t)(base + 2) * 32 + row) * 2);
  if (S > 3) v3 = *reinterpret_cast<const float2*>(ml + ((size_t)(base + 3) * 32 + row) * 2);
  const float ms = fmaxf(fmaxf(v0.x, v1.x), fmaxf(v2.x, v3.x));
  float c0 = __builtin_amdgcn_exp2f(v0.x - ms) * v0.y;
  float c1 = __builtin_amdgcn_exp2f(v1.x - ms) * v1.y;
  float c2 = __builtin_amdgcn_exp2f(v2.x - ms) * v2.y;  // 0 when S<=2
  float c3 = __builtin_amdgcn_exp2f(v3.x - ms) * v3.y;  // 0 when S<=3
  const float inv = 1.0f / (((c0 + c1) + (c2 + c3)));
  c0 *= inv; c1 *= inv; c2 *= inv; c3 *= inv;
  const int b = bh >> 3, h = bh & 7;
  const size_t rowo = (size_t)(b * 4096 + qt * 32 + row) * 512 + h * 64 + dh;
  const ushort* p0 = po + ((size_t)(base + 0) * 32 + row) * 64 + dh;
  const ushort* p1 = po + ((size_t)(base + 1) * 32 + row) * 64 + dh;
  const ushort* p2 = po + ((size_t)(base + 2) * 32 + row) * 64 + dh;
  const ushort* p3 = po + ((size_t)(base + 3) * 32 + row) * 64 + dh;
#pragma unroll
  for (int j = 0; j < 4; ++j) {
    float acc0 = 0.f, acc1 = 0.f, acc2 = 0.f, acc3 = 0.f;
    float acc4 = 0.f, acc5 = 0.f, acc6 = 0.f, acc7 = 0.f;
    {
      uint4 a = reinterpret_cast<const uint4*>(p0)[j];
      acc0 += c0 * bflo(a.x); acc1 += c0 * bfhi(a.x);
      acc2 += c0 * bflo(a.y); acc3 += c0 * bfhi(a.y);
      acc4 += c0 * bflo(a.z); acc5 += c0 * bfhi(a.z);
      acc6 += c0 * bflo(a.w); acc7 += c0 * bfhi(a.w);
    }
    {
      uint4 a = reinterpret_cast<const uint4*>(p1)[j];
      acc0 += c1 * bflo(a.x); acc1 += c1 * bfhi(a.x);
      acc2 += c1 * bflo(a.y); acc3 += c1 * bfhi(a.y);
      acc4 += c1 * bflo(a.z); acc5 += c1 * bfhi(a.z);
      acc6 += c1 * bflo(a.w); acc7 += c1 * bfhi(a.w);
    }
    if (S > 2) {
      uint4 a = reinterpret_cast<const uint4*>(p2)[j];
      acc0 += c2 * bflo(a.x); acc1 += c2 * bfhi(a.x);
      acc2 += c2 * bflo(a.y); acc3 += c2 * bfhi(a.y);
      acc4 += c2 * bflo(a.z); acc5 += c2 * bfhi(a.z);
      acc6 += c2 * bflo(a.w); acc7 += c2 * bfhi(a.w);
    }
    if (S > 3) {
      uint4 a = reinterpret_cast<const uint4*>(p3)[j];
      acc0 += c3 * bflo(a.x); acc1 += c3 * bfhi(a.x);
      acc2 += c3 * bflo(a.y); acc3 += c3 * bfhi(a.y);
      acc4 += c3 * bflo(a.z); acc5 += c3 * bfhi(a.z);
      acc6 += c3 * bflo(a.w); acc7 += c3 * bfhi(a.w);
    }
    uint4 out;
    out.x = cvt_pk_bf16(acc0, acc1);
    out.y = cvt_pk_bf16(acc2, acc3);
    out.z = cvt_pk_bf16(acc4, acc5);
    out.w = cvt_pk_bf16(acc6, acc7);
    reinterpret_cast<uint4*>(&O[rowo])[j] = out;
  }
}

extern "C" void kernel_launch(void* const* d_in, const int* in_sizes, int n_in,
                              void* d_out, int out_size, void* d_ws, size_t ws_size,
                              hipStream_t stream) {
  const float* x = (const float*)d_in[0];       // [2,4096,512]
  const float* w_qkv = (const float*)d_in[1];   // [1536,512]
  const float* w_proj = (const float*)d_in[2];  // [512,512]
  const float* b_proj = (const float*)d_in[3];  // [512]
  float* out = (float*)d_out;                   // [2,4096,512]

  ushort* xb = (ushort*)d_ws;                       // 8192*512   (reused as po, MODE 0)
  ushort* wqkvb = xb + (size_t)8192 * 512;          // 1536*512   (reused as ml, MODE 0)
  ushort* wprojb = wqkvb + (size_t)1536 * 512;      // 512*512
  ushort* qws = wprojb + (size_t)512 * 512;         // 16*4096*64
  ushort* kws = qws + (size_t)16 * 4096 * 64;
  ushort* vtws = kws + (size_t)16 * 4096 * 64;
  ushort* ows = vtws + (size_t)16 * 4096 * 64;      // 8192*512

  cvt_all<<<5120, 256, 0, stream>>>(x, w_qkv, w_proj, xb, wqkvb, wprojb);

  gemm_bt<0><<<dim3(12, 64), 256, 0, stream>>>(xb, wqkvb, qws, kws, vtws, nullptr, nullptr);

  // MODE 1 needs po4 (6144 slots x 32 rows x 64 d bf16 = 25.2MB) + ml4 (1.6MB)
  // placed after ows -> total ws requirement 70,778,880 B. Else fall back to MODE 0.
  ushort* po4 = ows + (size_t)8192 * 512;
  float* ml4 = (float*)(po4 + (size_t)6144 * 2048);
  const bool big = ws_size >= (size_t)70778880;

  if (big) {
    attn_kernel<1><<<5120, 64, 0, stream>>>(qws, kws, vtws, ows, po4, ml4);
    attn_merge4<<<1536, 64, 0, stream>>>(po4, ml4, ows);
  } else {
    ushort* po = xb;             // MODE 0: reuse dead cvt buffers
    float* ml = (float*)wqkvb;
    attn_kernel<0><<<3072, 64, 0, stream>>>(qws, kws, vtws, ows, po, ml);
    attn_merge<<<1024, 64, 0, stream>>>(po, ml, ows);
  }

  gemm_bt<1><<<dim3(4, 64), 256, 0, stream>>>(ows, wprojb, nullptr, nullptr, nullptr, out,
                                              b_proj);
}

// Round 15
// 109.061 us; speedup vs baseline: 1.0224x; 1.0224x over previous
//
#include <hip/hip_runtime.h>
#include <hip/hip_bf16.h>

// MultiHeadCausalSelfAttention: B=2, N=4096, C=512, H=8, D=64, causal, fp32 in/out.
// Pipeline: cvt(fused) -> QKV GEMM (scatter Q, frag-layout K/V) -> attn(+merge) -> proj.
// R15: attn restructured to 4-wave blocks sharing K/V tiles via double-buffered LDS
// (GEMM-dbuf-proven barrier skeleton; L2 traffic /4). Per-wave math identical R13.

typedef __attribute__((ext_vector_type(8))) short s16x8;   // 8 bf16 = one MFMA A/B frag
typedef __attribute__((ext_vector_type(4))) float f32x4;   // one MFMA C/D frag

#define QSCALE 0.18033688011112042f  // D^-0.5 * log2(e), folded into Q

__device__ __forceinline__ ushort f2bf(float f) {
  unsigned u = __float_as_uint(f);
  u = (u + 0x7FFFu + ((u >> 16) & 1u)) >> 16;  // RNE
  return (ushort)u;
}

__device__ __forceinline__ unsigned cvt_pk_bf16(float a, float b) {
  unsigned r;
  asm("v_cvt_pk_bf16_f32 %0, %1, %2" : "=v"(r) : "v"(a), "v"(b));
  return r;  // low16 = bf16(a), high16 = bf16(b)
}

__device__ __forceinline__ float bflo(unsigned u) { return __uint_as_float(u << 16); }
__device__ __forceinline__ float bfhi(unsigned u) { return __uint_as_float(u & 0xffff0000u); }

// One fused cvt for x (1048576 float4), w_qkv (196608), w_proj (65536).
__global__ __launch_bounds__(256) void cvt_all(const float* __restrict__ x,
                                               const float* __restrict__ wq,
                                               const float* __restrict__ wp,
                                               ushort* __restrict__ xb,
                                               ushort* __restrict__ wqb,
                                               ushort* __restrict__ wpb) {
  int i = blockIdx.x * 256 + threadIdx.x;
  const float* src;
  ushort* dst;
  int off;
  if (i < 1048576) {
    src = x; dst = xb; off = i;
  } else if (i < 1245184) {
    src = wq; dst = wqb; off = i - 1048576;
  } else {
    src = wp; dst = wpb; off = i - 1245184;
  }
  float4 v = reinterpret_cast<const float4*>(src)[off];
  ushort4 o;
  o.x = f2bf(v.x); o.y = f2bf(v.y); o.z = f2bf(v.z); o.w = f2bf(v.w);
  reinterpret_cast<ushort4*>(dst)[off] = o;
}

// C = A[M,512] @ W[Nout,512]^T, bf16 MFMA, 128x128 tile, 4 waves (2x2), BK=32.
// 2-phase double-buffer: STAGE(t+1) issued before compute(t), one barrier/iter.
// EPI 0: Q/K/V scatter. EPI 1: fp32 out + bias.
template <int EPI>
__global__ __launch_bounds__(256) void gemm_bt(const ushort* __restrict__ A,
                                               const ushort* __restrict__ W,
                                               ushort* __restrict__ q_ws,
                                               ushort* __restrict__ k_ws,
                                               ushort* __restrict__ vt_ws,
                                               float* __restrict__ outf,
                                               const float* __restrict__ bias) {
  __shared__ ushort As[2][128 * 32];
  __shared__ ushort Bs[2][128 * 32];
  const int tid = threadIdx.x;
  const int lane = tid & 63, wv = tid >> 6;
  const int wm = wv >> 1, wn = wv & 1;
  const int l15 = lane & 15, g = lane >> 4;
  const int tm = blockIdx.y * 128, tn = blockIdx.x * 128;

  f32x4 acc[4][4] = {};

#define GSTAGE(BUF, K0)                                                                    \
  do {                                                                                     \
    _Pragma("unroll") for (int it = 0; it < 2; ++it) {                                     \
      int slot = it * 256 + tid;                                                           \
      int row = slot >> 2;                                                                 \
      int ch = (slot & 3) ^ ((row >> 1) & 3);                                              \
      const int sb = (it * 256 + wv * 64) * 8; /* wave-uniform LDS base (ushorts) */       \
      __builtin_amdgcn_global_load_lds(                                                    \
          (const __attribute__((address_space(1))) void*)(A + (size_t)(tm + row) * 512 +   \
                                                          (K0) + ch * 8),                  \
          (__attribute__((address_space(3))) void*)(&As[BUF][0] + sb), 16, 0, 0);          \
      __builtin_amdgcn_global_load_lds(                                                    \
          (const __attribute__((address_space(1))) void*)(W + (size_t)(tn + row) * 512 +   \
                                                          (K0) + ch * 8),                  \
          (__attribute__((address_space(3))) void*)(&Bs[BUF][0] + sb), 16, 0, 0);          \
    }                                                                                      \
  } while (0)

  GSTAGE(0, 0);
  __syncthreads();
  int cur = 0;
  for (int t = 0; t < 16; ++t) {
    if (t < 15) GSTAGE(cur ^ 1, (t + 1) * 32);  // next tile in flight during compute
    s16x8 af[4], bfr[4];
#pragma unroll
    for (int i = 0; i < 4; ++i) {
      int Ra = wm * 64 + i * 16 + l15;
      af[i] = reinterpret_cast<const s16x8*>(&As[cur][0])[Ra * 4 + (g ^ ((Ra >> 1) & 3))];
      int Rb = wn * 64 + i * 16 + l15;
      bfr[i] = reinterpret_cast<const s16x8*>(&Bs[cur][0])[Rb * 4 + (g ^ ((Rb >> 1) & 3))];
    }
#pragma unroll
    for (int mi = 0; mi < 4; ++mi)
#pragma unroll
      for (int ni = 0; ni < 4; ++ni)
        acc[mi][ni] =
            __builtin_amdgcn_mfma_f32_16x16x32_bf16(af[mi], bfr[ni], acc[mi][ni], 0, 0, 0);
    __syncthreads();  // drains vmcnt (staged loads) + lgkm; both buffers safe
    cur ^= 1;
  }
#undef GSTAGE

  // C/D layout: col = lane&15, row = (lane>>4)*4 + reg   [measured m89/m91]
  const int rowb = tm + wm * 64 + g * 4;
  const int colb = tn + wn * 64 + l15;
#pragma unroll
  for (int mi = 0; mi < 4; ++mi) {
#pragma unroll
    for (int ni = 0; ni < 4; ++ni) {
      int r0 = rowb + mi * 16;
      int col = colb + ni * 16;
      if (EPI == 0) {
        int i3 = col >> 9, h = (col >> 6) & 7, d = col & 63;
        int b = r0 >> 12;
        int bh = b * 8 + h;
        if (i3 == 2) {
          int n0 = r0 & 4095;
          int kt = n0 >> 6, ce = (n0 >> 5) & 1, ge = (n0 >> 3) & 3, je = n0 & 7;
          int nbe = d >> 4, le = d & 15;
          ushort4 pk;
          pk.x = f2bf(acc[mi][ni][0]);
          pk.y = f2bf(acc[mi][ni][1]);
          pk.z = f2bf(acc[mi][ni][2]);
          pk.w = f2bf(acc[mi][ni][3]);
          *reinterpret_cast<ushort4*>(
              vt_ws + (((size_t)bh * 64 + kt) * 8 + nbe * 2 + ce) * 512 + (ge * 16 + le) * 8 +
              je) = pk;
        } else if (i3 == 1) {
          int ce = d >> 5, ge = (d >> 3) & 3, je = d & 7;
#pragma unroll
          for (int r = 0; r < 4; ++r) {
            int n = (r0 + r) & 4095;
            int kt = n >> 6, le = n & 15, nbe = (n >> 4) & 3;
            k_ws[(((size_t)bh * 64 + kt) * 8 + nbe * 2 + ce) * 512 + (ge * 16 + le) * 8 + je] =
                f2bf(acc[mi][ni][r]);
          }
        } else {
          int n0 = r0 & 4095;
#pragma unroll
          for (int r = 0; r < 4; ++r)
            q_ws[((size_t)bh * 4096 + (n0 + r)) * 64 + d] = f2bf(acc[mi][ni][r] * QSCALE);
        }
      } else {
#pragma unroll
        for (int r = 0; r < 4; ++r)
          outf[(size_t)(r0 + r) * 512 + col] = acc[mi][ni][r] + bias[col];
      }
    }
  }
}

// Flash attention, causal. 1024 x 256-thread (4-wave) blocks.
// Block = (bh, group G of 4 q-tiles qt=4G+wv, half h). K/V tiles (8KB contiguous in
// frag layout) staged ONCE per block into double-buffered LDS via global_load_lds;
// all 4 waves consume -> L2 traffic /4. Barrier skeleton = proven GEMM dbuf.
// Halves: h0 kt in [0,G], h1 [G+1, 2G+1] (mid=G+1 uniform across the 4 waves).
// All outputs -> normalized bf16 partials + (m,l); attn_merge combines.
// XCD-chunked (p = L&7 owns bh {2p,2p+1}); serpentine rank order for CU balance.
__global__ __launch_bounds__(256, 3) void attn_kernel(const ushort* __restrict__ Q,
                                                      const ushort* __restrict__ Kk,
                                                      const ushort* __restrict__ Vt,
                                                      ushort* __restrict__ po,
                                                      float* __restrict__ ml) {
  __shared__ ushort Ks[2][4096];      // 8KB K tile x2
  __shared__ ushort Vs[2][4096];      // 8KB V tile x2
  __shared__ ushort P_lds[4][32 * 64];  // per-wave P transpose buffer (swizzled)
  const int tid = threadIdx.x;
  const int lane = tid & 63, wv = tid >> 6;
  const int l15 = lane & 15, g = lane >> 4;
  const int L = blockIdx.x;            // 0..1023
  const int p = L & 7;                 // XCD
  int j2 = L >> 3;                     // 0..127
  {                                    // serpentine quarters for per-CU LPT balance
    const int pos = j2 & 31, quarter = j2 >> 5;
    if (quarter & 1) j2 = quarter * 32 + (31 - pos);
  }
  const int bh = p * 2 + (j2 & 1);     // each XCD: 2 bh only (K/V in its L2)
  const int i = j2 >> 1;               // 0..63, ascending = descending duration
  const int G = 31 - (i >> 1);         // q-group
  const int h = i & 1;                 // kt half
  const int qt = 4 * G + wv;           // this wave's q-tile
  const int ktmax = qt >> 1;           // diagonal tile index
  const int mid = G + 1;               // uniform split point across the 4 waves
  const int klo = h ? mid : 0;
  const int khi = h ? ktmax : (mid - 1);
  const int KLO = h ? mid : 0;         // block-uniform staging range
  const int KHI = h ? (2 * G + 1) : (mid - 1);
  const int slot = (bh * 128 + qt) * 2 + h;
  const int qw = qt * 32;
  const size_t baseQ = (size_t)bh * 4096 * 64;

  // Q B-frags: sub s -> query qw + s*16 + l15, k-elems c*32 + g*8 + j
  s16x8 aq[2][2];
#pragma unroll
  for (int s = 0; s < 2; ++s) {
    const ushort* qp = Q + baseQ + (size_t)(qw + s * 16 + l15) * 64 + g * 8;
    aq[s][0] = *reinterpret_cast<const s16x8*>(qp);
    aq[s][1] = *reinterpret_cast<const s16x8*>(qp + 32);
  }

  f32x4 o[2][4] = {};
  float m[2] = {-1e30f, -1e30f};
  float l[2] = {0.f, 0.f};  // per-lane PARTIAL sums (reduced in epilogue)
  const int swz = (l15 & 7) << 3;  // XOR swizzle in ushort units (16B granule)
  ushort* pl = P_lds[wv];

  // Shared staging: K/V tile (KT) -> LDS buffer BUF. 256 threads x 2 chunks x (K,V).
  // Tiles are 4096 contiguous ushorts in the frag layout -> linear copy.
#define KVSTAGE(BUF, KT)                                                                  \
  do {                                                                                    \
    const ushort* kSrc = Kk + ((size_t)bh * 64 + (KT)) * 4096;                            \
    const ushort* vSrc = Vt + ((size_t)bh * 64 + (KT)) * 4096;                            \
    _Pragma("unroll") for (int c = 0; c < 2; ++c) {                                       \
      const int sb = (c * 256 + wv * 64) * 8; /* wave-uniform LDS base (ushorts) */       \
      __builtin_amdgcn_global_load_lds(                                                   \
          (const __attribute__((address_space(1))) void*)(kSrc + sb + lane * 8),          \
          (__attribute__((address_space(3))) void*)(&Ks[BUF][0] + sb), 16, 0, 0);         \
      __builtin_amdgcn_global_load_lds(                                                   \
          (const __attribute__((address_space(1))) void*)(vSrc + sb + lane * 8),          \
          (__attribute__((address_space(3))) void*)(&Vs[BUF][0] + sb), 16, 0, 0);         \
    }                                                                                     \
  } while (0)

  KVSTAGE(0, KLO);
  __syncthreads();
  int cur = 0;
  for (int kt = KLO; kt <= KHI; ++kt) {
    if (kt < KHI) KVSTAGE(cur ^ 1, kt + 1);  // next tile in flight during compute
    if (kt >= klo && kt <= khi) {            // wave-local causal range (no barriers inside)
      const ushort* kl = &Ks[cur][lane * 8];
      const ushort* vl = &Vs[cur][lane * 8];
      s16x8 kf[8], vf[8];
#pragma unroll
      for (int t = 0; t < 8; ++t) kf[t] = *reinterpret_cast<const s16x8*>(kl + t * 512);
#pragma unroll
      for (int t = 0; t < 8; ++t) vf[t] = *reinterpret_cast<const s16x8*>(vl + t * 512);
      f32x4 st[2][4] = {};
      __builtin_amdgcn_s_setprio(1);
#pragma unroll
      for (int nb = 0; nb < 4; ++nb)
#pragma unroll
        for (int s = 0; s < 2; ++s) {
          st[s][nb] = __builtin_amdgcn_mfma_f32_16x16x32_bf16(kf[nb * 2 + 0], aq[s][0],
                                                              st[s][nb], 0, 0, 0);
          st[s][nb] = __builtin_amdgcn_mfma_f32_16x16x32_bf16(kf[nb * 2 + 1], aq[s][1],
                                                              st[s][nb], 0, 0, 0);
        }
      __builtin_amdgcn_s_setprio(0);
      if (kt == ktmax) {  // diagonal: mask key > query
        const int k0d = kt * 64;
#pragma unroll
        for (int s = 0; s < 2; ++s)
#pragma unroll
          for (int nb = 0; nb < 4; ++nb)
#pragma unroll
            for (int r2 = 0; r2 < 4; ++r2)
              if (k0d + nb * 16 + g * 4 + r2 > qw + s * 16 + l15) st[s][nb][r2] = -1e30f;
      }
#pragma unroll
      for (int s = 0; s < 2; ++s) {
        float a0 = fmaxf(fmaxf(st[s][0][0], st[s][0][1]), fmaxf(st[s][0][2], st[s][0][3]));
        float a1 = fmaxf(fmaxf(st[s][1][0], st[s][1][1]), fmaxf(st[s][1][2], st[s][1][3]));
        float a2 = fmaxf(fmaxf(st[s][2][0], st[s][2][1]), fmaxf(st[s][2][2], st[s][2][3]));
        float a3 = fmaxf(fmaxf(st[s][3][0], st[s][3][1]), fmaxf(st[s][3][2], st[s][3][3]));
        float pm = fmaxf(fmaxf(a0, a1), fmaxf(a2, a3));  // lane-local max
        if (!__all(pm - m[s] <= 8.0f)) {  // rare: full reduce + rescale
          float pmf = fmaxf(pm, __shfl_xor(pm, 16));
          pmf = fmaxf(pmf, __shfl_xor(pmf, 32));
          const float mn = fmaxf(m[s], pmf);
          const float al = __builtin_amdgcn_exp2f(m[s] - mn);
          l[s] *= al;
          m[s] = mn;
#pragma unroll
          for (int nb = 0; nb < 4; ++nb)
#pragma unroll
            for (int r2 = 0; r2 < 4; ++r2) o[s][nb][r2] *= al;
        }
        float rs = 0.f;
#pragma unroll
        for (int nb = 0; nb < 4; ++nb) {
          float p0 = __builtin_amdgcn_exp2f(st[s][nb][0] - m[s]);
          float p1 = __builtin_amdgcn_exp2f(st[s][nb][1] - m[s]);
          float p2 = __builtin_amdgcn_exp2f(st[s][nb][2] - m[s]);
          float p3 = __builtin_amdgcn_exp2f(st[s][nb][3] - m[s]);
          rs += (p0 + p1) + (p2 + p3);
          uint2 w;
          w.x = cvt_pk_bf16(p0, p1);
          w.y = cvt_pk_bf16(p2, p3);
          *reinterpret_cast<uint2*>(pl + (s * 16 + l15) * 64 + ((nb * 16 + g * 4) ^ swz)) = w;
        }
        l[s] += rs;
      }
      s16x8 pa[2][2];
#pragma unroll
      for (int s = 0; s < 2; ++s)
#pragma unroll
        for (int c = 0; c < 2; ++c)
          pa[s][c] = *reinterpret_cast<const s16x8*>(pl + (s * 16 + l15) * 64 +
                                                     ((c * 32 + g * 8) ^ swz));
      __builtin_amdgcn_s_setprio(1);
#pragma unroll
      for (int nb = 0; nb < 4; ++nb)
#pragma unroll
        for (int s = 0; s < 2; ++s) {
          o[s][nb] = __builtin_amdgcn_mfma_f32_16x16x32_bf16(vf[nb * 2 + 0], pa[s][0],
                                                             o[s][nb], 0, 0, 0);
          o[s][nb] = __builtin_amdgcn_mfma_f32_16x16x32_bf16(vf[nb * 2 + 1], pa[s][1],
                                                             o[s][nb], 0, 0, 0);
        }
      __builtin_amdgcn_s_setprio(0);
    }
    __syncthreads();  // drains staged loads + all LDS reads; buffers safe to swap
    cur ^= 1;
  }
#undef KVSTAGE

  // Reduce partial l across the 4 lane-groups (row sum per query l15).
  float lr[2];
#pragma unroll
  for (int s = 0; s < 2; ++s) {
    float ls = l[s];
    ls += __shfl_xor(ls, 16);
    ls += __shfl_xor(ls, 32);
    lr[s] = ls;
  }

  // Normalized bf16 partial O + (m, l) per row.  (All tiles go through merge.)
#pragma unroll
  for (int s = 0; s < 2; ++s) {
    const float linv = (lr[s] > 0.f) ? (1.0f / lr[s]) : 0.f;
    const int row = s * 16 + l15;
    const size_t pbase = ((size_t)slot * 32 + row) * 64;
#pragma unroll
    for (int nb = 0; nb < 4; ++nb) {
      uint2 pk;
      pk.x = cvt_pk_bf16(o[s][nb][0] * linv, o[s][nb][1] * linv);
      pk.y = cvt_pk_bf16(o[s][nb][2] * linv, o[s][nb][3] * linv);
      *reinterpret_cast<uint2*>(po + pbase + nb * 16 + g * 4) = pk;
    }
    if (g == 0) {
      float2 v;
      v.x = m[s];
      v.y = lr[s];
      *reinterpret_cast<float2*>(ml + ((size_t)slot * 32 + row) * 2) = v;
    }
  }
}

// Merge the two KV-halves of every q-tile. 2048 blocks x 64 threads.
__global__ __launch_bounds__(64) void attn_merge(const ushort* __restrict__ po,
                                                 const float* __restrict__ ml,
                                                 ushort* __restrict__ O) {
  const int M = blockIdx.x, tid = threadIdx.x;
  const int p = M & 7, q2 = M >> 3;   // q2 0..255
  const int bh = p * 2 + (q2 & 1);
  const int qt = q2 >> 1;             // 0..127
  const int t = bh * 128 + qt;
  const int row = tid >> 1, dh = (tid & 1) * 32;
  const float2 ml0 = *reinterpret_cast<const float2*>(ml + ((size_t)(t * 2 + 0) * 32 + row) * 2);
  const float2 ml1 = *reinterpret_cast<const float2*>(ml + ((size_t)(t * 2 + 1) * 32 + row) * 2);
  const float ms = fmaxf(ml0.x, ml1.x);
  const float w0 = __builtin_amdgcn_exp2f(ml0.x - ms) * ml0.y;
  const float w1 = __builtin_amdgcn_exp2f(ml1.x - ms) * ml1.y;
  const float inv = 1.0f / (w0 + w1);
  const float c0 = w0 * inv, c1 = w1 * inv;
  const int b = bh >> 3, h = bh & 7;
  const size_t rowo = (size_t)(b * 4096 + qt * 32 + row) * 512 + h * 64 + dh;
  const ushort* p0 = po + ((size_t)(t * 2 + 0) * 32 + row) * 64 + dh;
  const ushort* p1 = po + ((size_t)(t * 2 + 1) * 32 + row) * 64 + dh;
#pragma unroll
  for (int j = 0; j < 4; ++j) {
    uint4 a = reinterpret_cast<const uint4*>(p0)[j];
    uint4 bb = reinterpret_cast<const uint4*>(p1)[j];
    uint4 out;
    out.x = cvt_pk_bf16(c0 * bflo(a.x) + c1 * bflo(bb.x), c0 * bfhi(a.x) + c1 * bfhi(bb.x));
    out.y = cvt_pk_bf16(c0 * bflo(a.y) + c1 * bflo(bb.y), c0 * bfhi(a.y) + c1 * bfhi(bb.y));
    out.z = cvt_pk_bf16(c0 * bflo(a.z) + c1 * bflo(bb.z), c0 * bfhi(a.z) + c1 * bfhi(bb.z));
    out.w = cvt_pk_bf16(c0 * bflo(a.w) + c1 * bflo(bb.w), c0 * bfhi(a.w) + c1 * bfhi(bb.w));
    reinterpret_cast<uint4*>(&O[rowo])[j] = out;
  }
}

extern "C" void kernel_launch(void* const* d_in, const int* in_sizes, int n_in,
                              void* d_out, int out_size, void* d_ws, size_t ws_size,
                              hipStream_t stream) {
  const float* x = (const float*)d_in[0];       // [2,4096,512]
  const float* w_qkv = (const float*)d_in[1];   // [1536,512]
  const float* w_proj = (const float*)d_in[2];  // [512,512]
  const float* b_proj = (const float*)d_in[3];  // [512]
  float* out = (float*)d_out;                   // [2,4096,512]

  ushort* xb = (ushort*)d_ws;                       // 8192*512
  ushort* wqkvb = xb + (size_t)8192 * 512;          // 1536*512
  ushort* wprojb = wqkvb + (size_t)1536 * 512;      // 512*512
  ushort* qws = wprojb + (size_t)512 * 512;         // 16*4096*64
  ushort* kws = qws + (size_t)16 * 4096 * 64;
  ushort* vtws = kws + (size_t)16 * 4096 * 64;
  ushort* ows = vtws + (size_t)16 * 4096 * 64;      // 8192*512

  cvt_all<<<5120, 256, 0, stream>>>(x, w_qkv, w_proj, xb, wqkvb, wprojb);

  gemm_bt<0><<<dim3(12, 64), 256, 0, stream>>>(xb, wqkvb, qws, kws, vtws, nullptr, nullptr);

  // Partials at ws tail: po = 2048 q-tiles x 2 halves x (32 rows x 64 d) bf16 = 16.8MB,
  // ml = 1MB -> total 61.9MB (ws >= 70.8MB verified by R14's big path running).
  ushort* po = ows + (size_t)8192 * 512;
  float* ml = (float*)(po + (size_t)2048 * 2 * 32 * 64);

  attn_kernel<<<1024, 256, 0, stream>>>(qws, kws, vtws, po, ml);
  attn_merge<<<2048, 64, 0, stream>>>(po, ml, ows);

  gemm_bt<1><<<dim3(4, 64), 256, 0, stream>>>(ows, wprojb, nullptr, nullptr, nullptr, out,
                                              b_proj);
}

// Round 16
// 107.820 us; speedup vs baseline: 1.0341x; 1.0115x over previous
//
#include <hip/hip_runtime.h>
#include <hip/hip_bf16.h>

// MultiHeadCausalSelfAttention: B=2, N=4096, C=512, H=8, D=64, causal, fp32 in/out.
// Pipeline: cvt(fused) -> QKV GEMM (scatter Q,K,V frag layouts) -> attn(+merge) -> proj.
// R16: attn compute body ported to 32x32x16 MFMA with fully in-register softmax and
// cvt_pk+permlane32_swap P-redistribution (no P-LDS roundtrip, no steady-state shfl).
// Block/staging/halves/partials skeleton unchanged from R15 (proven).

typedef __attribute__((ext_vector_type(8))) short s16x8;    // 8 bf16 = MFMA A/B frag
typedef __attribute__((ext_vector_type(4))) float f32x4;    // 16x16 C/D frag
typedef __attribute__((ext_vector_type(16))) float f32x16;  // 32x32 C/D frag
typedef __attribute__((ext_vector_type(4))) unsigned u32x4;

#define QSCALE 0.18033688011112042f  // D^-0.5 * log2(e), folded into Q

__device__ __forceinline__ ushort f2bf(float f) {
  unsigned u = __float_as_uint(f);
  u = (u + 0x7FFFu + ((u >> 16) & 1u)) >> 16;  // RNE
  return (ushort)u;
}

__device__ __forceinline__ unsigned cvt_pk_bf16(float a, float b) {
  unsigned r;
  asm("v_cvt_pk_bf16_f32 %0, %1, %2" : "=v"(r) : "v"(a), "v"(b));
  return r;  // low16 = bf16(a), high16 = bf16(b)
}

__device__ __forceinline__ float bflo(unsigned u) { return __uint_as_float(u << 16); }
__device__ __forceinline__ float bfhi(unsigned u) { return __uint_as_float(u & 0xffff0000u); }

// One fused cvt for x (1048576 float4), w_qkv (196608), w_proj (65536).
__global__ __launch_bounds__(256) void cvt_all(const float* __restrict__ x,
                                               const float* __restrict__ wq,
                                               const float* __restrict__ wp,
                                               ushort* __restrict__ xb,
                                               ushort* __restrict__ wqb,
                                               ushort* __restrict__ wpb) {
  int i = blockIdx.x * 256 + threadIdx.x;
  const float* src;
  ushort* dst;
  int off;
  if (i < 1048576) {
    src = x; dst = xb; off = i;
  } else if (i < 1245184) {
    src = wq; dst = wqb; off = i - 1048576;
  } else {
    src = wp; dst = wpb; off = i - 1245184;
  }
  float4 v = reinterpret_cast<const float4*>(src)[off];
  ushort4 o;
  o.x = f2bf(v.x); o.y = f2bf(v.y); o.z = f2bf(v.z); o.w = f2bf(v.w);
  reinterpret_cast<ushort4*>(dst)[off] = o;
}

// C = A[M,512] @ W[Nout,512]^T, bf16 MFMA 16x16, 128x128 tile, 4 waves, BK=32, dbuf.
// EPI 0 scatter layouts (for 32x32 attn frags):
//  Q: [(bh*128+qt)*2048 + (dt*64 + (q&31) + 32*((d>>3)&1))*8 + (d&7)]   (xQSCALE)
//  K: [(bh*64+kt64)*4096 + ((kb*4+dt)*64 + (key&31) + 32*((d>>3)&1))*8 + (d&7)]
//  V: [(bh*64+kt64)*4096 + ((db*4+kc)*64 + (d&31) + 32*((key>>3)&1))*8 + (key&7)]
// EPI 1: fp32 out + bias.
template <int EPI>
__global__ __launch_bounds__(256) void gemm_bt(const ushort* __restrict__ A,
                                               const ushort* __restrict__ W,
                                               ushort* __restrict__ q_ws,
                                               ushort* __restrict__ k_ws,
                                               ushort* __restrict__ vt_ws,
                                               float* __restrict__ outf,
                                               const float* __restrict__ bias) {
  __shared__ ushort As[2][128 * 32];
  __shared__ ushort Bs[2][128 * 32];
  const int tid = threadIdx.x;
  const int lane = tid & 63, wv = tid >> 6;
  const int wm = wv >> 1, wn = wv & 1;
  const int l15 = lane & 15, g = lane >> 4;
  const int tm = blockIdx.y * 128, tn = blockIdx.x * 128;

  f32x4 acc[4][4] = {};

#define GSTAGE(BUF, K0)                                                                    \
  do {                                                                                     \
    _Pragma("unroll") for (int it = 0; it < 2; ++it) {                                     \
      int slot = it * 256 + tid;                                                           \
      int row = slot >> 2;                                                                 \
      int ch = (slot & 3) ^ ((row >> 1) & 3);                                              \
      const int sb = (it * 256 + wv * 64) * 8; /* wave-uniform LDS base (ushorts) */       \
      __builtin_amdgcn_global_load_lds(                                                    \
          (const __attribute__((address_space(1))) void*)(A + (size_t)(tm + row) * 512 +   \
                                                          (K0) + ch * 8),                  \
          (__attribute__((address_space(3))) void*)(&As[BUF][0] + sb), 16, 0, 0);          \
      __builtin_amdgcn_global_load_lds(                                                    \
          (const __attribute__((address_space(1))) void*)(W + (size_t)(tn + row) * 512 +   \
                                                          (K0) + ch * 8),                  \
          (__attribute__((address_space(3))) void*)(&Bs[BUF][0] + sb), 16, 0, 0);          \
    }                                                                                      \
  } while (0)

  GSTAGE(0, 0);
  __syncthreads();
  int cur = 0;
  for (int t = 0; t < 16; ++t) {
    if (t < 15) GSTAGE(cur ^ 1, (t + 1) * 32);
    s16x8 af[4], bfr[4];
#pragma unroll
    for (int i = 0; i < 4; ++i) {
      int Ra = wm * 64 + i * 16 + l15;
      af[i] = reinterpret_cast<const s16x8*>(&As[cur][0])[Ra * 4 + (g ^ ((Ra >> 1) & 3))];
      int Rb = wn * 64 + i * 16 + l15;
      bfr[i] = reinterpret_cast<const s16x8*>(&Bs[cur][0])[Rb * 4 + (g ^ ((Rb >> 1) & 3))];
    }
#pragma unroll
    for (int mi = 0; mi < 4; ++mi)
#pragma unroll
      for (int ni = 0; ni < 4; ++ni)
        acc[mi][ni] =
            __builtin_amdgcn_mfma_f32_16x16x32_bf16(af[mi], bfr[ni], acc[mi][ni], 0, 0, 0);
    __syncthreads();
    cur ^= 1;
  }
#undef GSTAGE

  // C/D (16x16): col = lane&15, row = (lane>>4)*4 + reg
  const int rowb = tm + wm * 64 + g * 4;
  const int colb = tn + wn * 64 + l15;
#pragma unroll
  for (int mi = 0; mi < 4; ++mi) {
#pragma unroll
    for (int ni = 0; ni < 4; ++ni) {
      int r0 = rowb + mi * 16;
      int col = colb + ni * 16;
      if (EPI == 0) {
        int i3 = col >> 9, h = (col >> 6) & 7, d = col & 63;
        int b = r0 >> 12;
        int bh = b * 8 + h;
        if (i3 == 2) {  // V: 4 consecutive keys -> ushort4 (j0 = n0&7 in {0,4})
          int n0 = r0 & 4095;
          int kt64 = n0 >> 6, key64 = n0 & 63;
          int kc = key64 >> 4, hk = (key64 >> 3) & 1, j0 = key64 & 7;
          int db = d >> 5, d31 = d & 31;
          ushort4 pk;
          pk.x = f2bf(acc[mi][ni][0]);
          pk.y = f2bf(acc[mi][ni][1]);
          pk.z = f2bf(acc[mi][ni][2]);
          pk.w = f2bf(acc[mi][ni][3]);
          *reinterpret_cast<ushort4*>(vt_ws + (size_t)(bh * 64 + kt64) * 4096 +
                                      ((db * 4 + kc) * 64 + d31 + 32 * hk) * 8 + j0) = pk;
        } else if (i3 == 1) {  // K: scalar x4
          int dt = d >> 4, hd = (d >> 3) & 1, j = d & 7;
#pragma unroll
          for (int r = 0; r < 4; ++r) {
            int n = (r0 + r) & 4095;
            int kt64 = n >> 6, key64 = n & 63;
            int kb = key64 >> 5, key31 = key64 & 31;
            k_ws[(size_t)(bh * 64 + kt64) * 4096 +
                 ((kb * 4 + dt) * 64 + key31 + 32 * hd) * 8 + j] = f2bf(acc[mi][ni][r]);
          }
        } else {  // Q: scalar x4, scaled
          int dt = d >> 4, hd = (d >> 3) & 1, j = d & 7;
#pragma unroll
          for (int r = 0; r < 4; ++r) {
            int n = (r0 + r) & 4095;
            int qt = n >> 5, q31 = n & 31;
            q_ws[(size_t)(bh * 128 + qt) * 2048 + (dt * 64 + q31 + 32 * hd) * 8 + j] =
                f2bf(acc[mi][ni][r] * QSCALE);
          }
        }
      } else {
#pragma unroll
        for (int r = 0; r < 4; ++r)
          outf[(size_t)(r0 + r) * 512 + col] = acc[mi][ni][r] + bias[col];
      }
    }
  }
}

// Flash attention, causal. 1024 x 256-thread (4-wave) blocks, 32x32x16 MFMA.
// Wave = one 32-row q-tile (qt = 4G+wv). K/V tiles (8KB each) double-buffered in LDS.
// Swapped QK^T: S^T 32x32 -> lane owns query lane&31, 32 of 64 keys in regs.
// Softmax in-register; P -> PV B-frags via cvt_pk + v_permlane32_swap_b32.
// Halves h0 [0,G], h1 [G+1, ktmax]; partials (normalized bf16 + m,l) -> merge.
__global__ __launch_bounds__(256, 2) void attn_kernel(const ushort* __restrict__ Q,
                                                      const ushort* __restrict__ Kk,
                                                      const ushort* __restrict__ Vt,
                                                      ushort* __restrict__ po,
                                                      float* __restrict__ ml) {
  __shared__ ushort Ks[2][4096];
  __shared__ ushort Vs[2][4096];
  const int tid = threadIdx.x;
  const int lane = tid & 63, wv = tid >> 6;
  const int l31 = lane & 31, hf = lane >> 5;
  const int L = blockIdx.x;            // 0..1023
  const int p = L & 7;                 // XCD
  int j2 = L >> 3;                     // 0..127
  {                                    // serpentine quarters for per-CU LPT balance
    const int pos = j2 & 31, quarter = j2 >> 5;
    if (quarter & 1) j2 = quarter * 32 + (31 - pos);
  }
  const int bh = p * 2 + (j2 & 1);     // each XCD: 2 bh only
  const int i = j2 >> 1;               // 0..63
  const int G = 31 - (i >> 1);         // q-group
  const int h = i & 1;                 // kt half
  const int qt = 4 * G + wv;           // this wave's q-tile (32 rows)
  const int ktmax = qt >> 1;           // diagonal tile index
  const int mid = G + 1;
  const int klo = h ? mid : 0;
  const int khi = h ? ktmax : (mid - 1);
  const int KLO = h ? mid : 0;
  const int KHI = h ? (2 * G + 1) : (mid - 1);
  const int slot = (bh * 128 + qt) * 2 + h;
  const int qw = qt * 32;

  // Q B-frags (32x32x16): col = lane&31 = query, k = (lane>>5)*8+j = d - dt*16
  s16x8 aq[4];
  {
    const ushort* qp = Q + ((size_t)bh * 128 + qt) * 2048 + lane * 8;
#pragma unroll
    for (int dt = 0; dt < 4; ++dt) aq[dt] = *reinterpret_cast<const s16x8*>(qp + dt * 512);
  }

  f32x16 o[2] = {};  // O^T acc: db in {0,1}; col=lane&31=query, row=d
  float m = -1e30f;
  float l = 0.f;  // per-lane partial over this lane's 32 keys/tile (pair-reduced at end)

#define KVSTAGE(BUF, KT)                                                                  \
  do {                                                                                    \
    const ushort* kSrc = Kk + ((size_t)bh * 64 + (KT)) * 4096;                            \
    const ushort* vSrc = Vt + ((size_t)bh * 64 + (KT)) * 4096;                            \
    _Pragma("unroll") for (int c = 0; c < 2; ++c) {                                       \
      const int sb = (c * 256 + wv * 64) * 8;                                             \
      __builtin_amdgcn_global_load_lds(                                                   \
          (const __attribute__((address_space(1))) void*)(kSrc + sb + lane * 8),          \
          (__attribute__((address_space(3))) void*)(&Ks[BUF][0] + sb), 16, 0, 0);         \
      __builtin_amdgcn_global_load_lds(                                                   \
          (const __attribute__((address_space(1))) void*)(vSrc + sb + lane * 8),          \
          (__attribute__((address_space(3))) void*)(&Vs[BUF][0] + sb), 16, 0, 0);         \
    }                                                                                     \
  } while (0)

  KVSTAGE(0, KLO);
  __syncthreads();
  int cur = 0;
  for (int kt = KLO; kt <= KHI; ++kt) {
    if (kt < KHI) KVSTAGE(cur ^ 1, kt + 1);
    if (kt >= klo && kt <= khi) {
      // K A-frags: row = lane&31 = key(+32*kb), k = (lane>>5)*8+j = d - dt*16
      const ushort* kl = &Ks[cur][lane * 8];
      s16x8 kf[8];
#pragma unroll
      for (int t = 0; t < 8; ++t) kf[t] = *reinterpret_cast<const s16x8*>(kl + t * 512);
      f32x16 st[2] = {};
      __builtin_amdgcn_s_setprio(1);
#pragma unroll
      for (int kb = 0; kb < 2; ++kb)
#pragma unroll
        for (int dt = 0; dt < 4; ++dt)
          st[kb] = __builtin_amdgcn_mfma_f32_32x32x16_bf16(kf[kb * 4 + dt], aq[dt],
                                                           st[kb], 0, 0, 0);
      __builtin_amdgcn_s_setprio(0);
      // C/D 32x32: col = lane&31 = query, row = (r&3)+8*(r>>2)+4*(lane>>5) = key(+32kb)
      if (kt == ktmax) {  // diagonal: mask key > query
        const int qg = qw + l31;
#pragma unroll
        for (int kb = 0; kb < 2; ++kb)
#pragma unroll
          for (int r = 0; r < 16; ++r)
            if (kt * 64 + kb * 32 + (r & 3) + 8 * (r >> 2) + 4 * hf > qg)
              st[kb][r] = -1e30f;
      }
      // lane-local max over this lane's 32 keys
      float mx[2];
#pragma unroll
      for (int kb = 0; kb < 2; ++kb) {
        float t0 = fmaxf(fmaxf(st[kb][0], st[kb][1]), fmaxf(st[kb][2], st[kb][3]));
        float t1 = fmaxf(fmaxf(st[kb][4], st[kb][5]), fmaxf(st[kb][6], st[kb][7]));
        float t2 = fmaxf(fmaxf(st[kb][8], st[kb][9]), fmaxf(st[kb][10], st[kb][11]));
        float t3 = fmaxf(fmaxf(st[kb][12], st[kb][13]), fmaxf(st[kb][14], st[kb][15]));
        mx[kb] = fmaxf(fmaxf(t0, t1), fmaxf(t2, t3));
      }
      float pm = fmaxf(mx[0], mx[1]);
      if (!__all(pm - m <= 8.0f)) {  // rare: joint (pair) max + rescale
        float pmf = fmaxf(pm, __shfl_xor(pm, 32));
        const float mn = fmaxf(m, pmf);
        const float al = __builtin_amdgcn_exp2f(m - mn);
        l *= al;
        m = mn;
#pragma unroll
        for (int db = 0; db < 2; ++db)
#pragma unroll
          for (int r = 0; r < 16; ++r) o[db][r] *= al;
      }
      // exp + pack into PV B-frags: pb[kc] k-elems = kc*16 + (lane>>5)*8 + j
      s16x8 pb[4];
      float rs = 0.f;
#pragma unroll
      for (int kb = 0; kb < 2; ++kb) {
        float e[16];
#pragma unroll
        for (int r = 0; r < 16; ++r) {
          e[r] = __builtin_amdgcn_exp2f(st[kb][r] - m);
          rs += e[r];
        }
        unsigned a0 = cvt_pk_bf16(e[0], e[1]), a1 = cvt_pk_bf16(e[2], e[3]);
        unsigned b0 = cvt_pk_bf16(e[4], e[5]), b1 = cvt_pk_bf16(e[6], e[7]);
        asm volatile("v_permlane32_swap_b32 %0, %1" : "+v"(a0), "+v"(b0));
        asm volatile("v_permlane32_swap_b32 %0, %1" : "+v"(a1), "+v"(b1));
        u32x4 w0;
        w0[0] = a0; w0[1] = a1; w0[2] = b0; w0[3] = b1;
        pb[kb * 2] = __builtin_bit_cast(s16x8, w0);
        unsigned c0 = cvt_pk_bf16(e[8], e[9]), c1 = cvt_pk_bf16(e[10], e[11]);
        unsigned d0 = cvt_pk_bf16(e[12], e[13]), d1 = cvt_pk_bf16(e[14], e[15]);
        asm volatile("v_permlane32_swap_b32 %0, %1" : "+v"(c0), "+v"(d0));
        asm volatile("v_permlane32_swap_b32 %0, %1" : "+v"(c1), "+v"(d1));
        u32x4 w1;
        w1[0] = c0; w1[1] = c1; w1[2] = d0; w1[3] = d1;
        pb[kb * 2 + 1] = __builtin_bit_cast(s16x8, w1);
      }
      l += rs;
      // V A-frags: row = lane&31 = d(+32*db), k = (lane>>5)*8+j = key - kc*16
      const ushort* vl = &Vs[cur][lane * 8];
      s16x8 vf[8];
#pragma unroll
      for (int t = 0; t < 8; ++t) vf[t] = *reinterpret_cast<const s16x8*>(vl + t * 512);
      __builtin_amdgcn_s_setprio(1);
#pragma unroll
      for (int db = 0; db < 2; ++db)
#pragma unroll
        for (int kc = 0; kc < 4; ++kc)
          o[db] = __builtin_amdgcn_mfma_f32_32x32x16_bf16(vf[db * 4 + kc], pb[kc],
                                                          o[db], 0, 0, 0);
      __builtin_amdgcn_s_setprio(0);
    }
    __syncthreads();  // drains staged loads + LDS reads; buffers safe to swap
    cur ^= 1;
  }
#undef KVSTAGE

  // l: pair-reduce (lane, lane+32) covers the full 64-key rows
  float lr = l + __shfl_xor(l, 32);
  const float linv = (lr > 0.f) ? (1.0f / lr) : 0.f;

  // Partial O: row = query = lane&31; o[db] reg r -> d = db*32 + 8*(r>>2) + 4*hf + (r&3)
  const size_t pbase = ((size_t)slot * 32 + l31) * 64;
#pragma unroll
  for (int db = 0; db < 2; ++db)
#pragma unroll
    for (int rg = 0; rg < 4; ++rg) {
      const int d0 = db * 32 + 8 * rg + 4 * hf;
      uint2 pk;
      pk.x = cvt_pk_bf16(o[db][rg * 4 + 0] * linv, o[db][rg * 4 + 1] * linv);
      pk.y = cvt_pk_bf16(o[db][rg * 4 + 2] * linv, o[db][rg * 4 + 3] * linv);
      *reinterpret_cast<uint2*>(po + pbase + d0) = pk;
    }
  if (hf == 0) {
    float2 v;
    v.x = m;
    v.y = lr;
    *reinterpret_cast<float2*>(ml + ((size_t)slot * 32 + l31) * 2) = v;
  }
}

// Merge the two KV-halves of every q-tile. 2048 blocks x 64 threads.
__global__ __launch_bounds__(64) void attn_merge(const ushort* __restrict__ po,
                                                 const float* __restrict__ ml,
                                                 ushort* __restrict__ O) {
  const int M = blockIdx.x, tid = threadIdx.x;
  const int p = M & 7, q2 = M >> 3;   // q2 0..255
  const int bh = p * 2 + (q2 & 1);
  const int qt = q2 >> 1;             // 0..127
  const int t = bh * 128 + qt;
  const int row = tid >> 1, dh = (tid & 1) * 32;
  const float2 ml0 = *reinterpret_cast<const float2*>(ml + ((size_t)(t * 2 + 0) * 32 + row) * 2);
  const float2 ml1 = *reinterpret_cast<const float2*>(ml + ((size_t)(t * 2 + 1) * 32 + row) * 2);
  const float ms = fmaxf(ml0.x, ml1.x);
  const float w0 = __builtin_amdgcn_exp2f(ml0.x - ms) * ml0.y;
  const float w1 = __builtin_amdgcn_exp2f(ml1.x - ms) * ml1.y;
  const float inv = 1.0f / (w0 + w1);
  const float c0 = w0 * inv, c1 = w1 * inv;
  const int b = bh >> 3, h = bh & 7;
  const size_t rowo = (size_t)(b * 4096 + qt * 32 + row) * 512 + h * 64 + dh;
  const ushort* p0 = po + ((size_t)(t * 2 + 0) * 32 + row) * 64 + dh;
  const ushort* p1 = po + ((size_t)(t * 2 + 1) * 32 + row) * 64 + dh;
#pragma unroll
  for (int j = 0; j < 4; ++j) {
    uint4 a = reinterpret_cast<const uint4*>(p0)[j];
    uint4 bb = reinterpret_cast<const uint4*>(p1)[j];
    uint4 out;
    out.x = cvt_pk_bf16(c0 * bflo(a.x) + c1 * bflo(bb.x), c0 * bfhi(a.x) + c1 * bfhi(bb.x));
    out.y = cvt_pk_bf16(c0 * bflo(a.y) + c1 * bflo(bb.y), c0 * bfhi(a.y) + c1 * bfhi(bb.y));
    out.z = cvt_pk_bf16(c0 * bflo(a.z) + c1 * bflo(bb.z), c0 * bfhi(a.z) + c1 * bfhi(bb.z));
    out.w = cvt_pk_bf16(c0 * bflo(a.w) + c1 * bflo(bb.w), c0 * bfhi(a.w) + c1 * bfhi(bb.w));
    reinterpret_cast<uint4*>(&O[rowo])[j] = out;
  }
}

extern "C" void kernel_launch(void* const* d_in, const int* in_sizes, int n_in,
                              void* d_out, int out_size, void* d_ws, size_t ws_size,
                              hipStream_t stream) {
  const float* x = (const float*)d_in[0];       // [2,4096,512]
  const float* w_qkv = (const float*)d_in[1];   // [1536,512]
  const float* w_proj = (const float*)d_in[2];  // [512,512]
  const float* b_proj = (const float*)d_in[3];  // [512]
  float* out = (float*)d_out;                   // [2,4096,512]

  ushort* xb = (ushort*)d_ws;                       // 8192*512
  ushort* wqkvb = xb + (size_t)8192 * 512;          // 1536*512
  ushort* wprojb = wqkvb + (size_t)1536 * 512;      // 512*512
  ushort* qws = wprojb + (size_t)512 * 512;         // 16*128*2048 = 4.19M
  ushort* kws = qws + (size_t)16 * 4096 * 64;       // 16*64*4096 = 4.19M
  ushort* vtws = kws + (size_t)16 * 4096 * 64;
  ushort* ows = vtws + (size_t)16 * 4096 * 64;      // 8192*512

  cvt_all<<<5120, 256, 0, stream>>>(x, w_qkv, w_proj, xb, wqkvb, wprojb);

  gemm_bt<0><<<dim3(12, 64), 256, 0, stream>>>(xb, wqkvb, qws, kws, vtws, nullptr, nullptr);

  // Partials at ws tail (fits: R14 big path verified ws >= 70.8MB).
  ushort* po = ows + (size_t)8192 * 512;
  float* ml = (float*)(po + (size_t)2048 * 2 * 32 * 64);

  attn_kernel<<<1024, 256, 0, stream>>>(qws, kws, vtws, po, ml);
  attn_merge<<<2048, 64, 0, stream>>>(po, ml, ows);

  gemm_bt<1><<<dim3(4, 64), 256, 0, stream>>>(ows, wprojb, nullptr, nullptr, nullptr, out,
                                              b_proj);
}